// Round 9
// baseline (118.299 us; speedup 1.0000x reference)
//
#include <hip/hip_runtime.h>
#include <hip/hip_bf16.h>
#include <math.h>

#define NS 256
#define T_LEN 8192
#define NF 32000
#define L_CH 8
#define B_BN 8
#define S_TOT 16          // B_BN + L_CH
#define C_CH 1024         // T_LEN / L_CH
#define G_CH 16           // chains per block
#define NBLK 64           // C_CH / G_CH
#define SCALE 32768.0f
#define XPAD 264          // shorts per x-row (528 B)

typedef short short8 __attribute__((ext_vector_type(8)));
typedef float f32x4 __attribute__((ext_vector_type(4)));

__device__ __forceinline__ short f2bs(float f) {
    union { __bf16 b; short s; } u; u.b = (__bf16)f; return u.s;
}
__device__ __forceinline__ float bs2f(short s) {
    union { short s; __bf16 b; } u; u.s = s; return (float)u.b;
}

// LDS-only barrier: drain own LDS ops, sync; global loads/stores ride across.
__device__ __forceinline__ void sync_lds_only() {
    __builtin_amdgcn_sched_barrier(0);
    asm volatile("s_waitcnt lgkmcnt(0)" ::: "memory");
    __builtin_amdgcn_s_barrier();
    __builtin_amdgcn_sched_barrier(0);
}

// ---- chained MFMA steps: 64 blocks x 512 threads (8 waves x 2 n-tiles) ----
// Emission gather fused (prefetch issued before the barrier -> latency hidden
// under a full step). A-fragments loaded directly from A, bf16-converted.
__global__ __launch_bounds__(512, 2)
void hmm_chains(const float* __restrict__ start,
                const float* __restrict__ A,
                const float* __restrict__ E,
                const int* __restrict__ obs,
                unsigned short* __restrict__ zbuf,   // [T][NS] bf16
                float* __restrict__ Pb, float* __restrict__ Qb)
{
    const int bid  = blockIdx.x;
    const int tid  = threadIdx.x;
    const int wv   = tid >> 6;          // wave 0..7
    const int lane = tid & 63;
    const int cj   = lane & 15;
    const int rq   = lane >> 4;
    const int base = 128 * bid - B_BN;  // t = base + 8*g + s

    __shared__ unsigned short xb[2][G_CH][XPAD];

    int cols[2];
#pragma unroll
    for (int nt = 0; nt < 2; ++nt) cols[nt] = (wv * 2 + nt) * 16 + cj;

    // B-fragments of A, loaded direct + converted: 16 x short8 = 64 VGPRs
    short8 bfr[2][8];
#pragma unroll
    for (int nt = 0; nt < 2; ++nt) {
#pragma unroll
        for (int kk = 0; kk < 8; ++kk) {
            float tv[8];
#pragma unroll
            for (int e = 0; e < 8; ++e)
                tv[e] = A[(size_t)(kk * 32 + rq * 8 + e) * NS + cols[nt]];
            short8 v;
#pragma unroll
            for (int e = 0; e < 8; ++e) v[e] = f2bs(tv[e]);
            bfr[nt][kk] = v;
        }
    }
#pragma unroll
    for (int nt = 0; nt < 2; ++nt)
#pragma unroll
        for (int kk = 0; kk < 8; ++kk)
            asm volatile("" : "+v"(bfr[nt][kk]));

    const int obs0 = obs[0];

    // burn-in start: x = 1 (bf16 0x3F80)
    for (int idx = tid; idx < G_CH * XPAD; idx += 512)
        ((unsigned short*)xb[0])[idx] = 0x3F80;

    // prologue: emissions for s = 1
    float evc[2][4], evn[2][4];
#pragma unroll
    for (int r = 0; r < 4; ++r) {
        int t = base + 8 * (rq * 4 + r) + 1;
        t = t < 0 ? 0 : t;
        int o = obs[t];
#pragma unroll
        for (int nt = 0; nt < 2; ++nt)
            evc[nt][r] = E[(size_t)cols[nt] * NF + o] * SCALE;
    }

    for (int s = 1; s < S_TOT; ++s) {
        // issue next step's gather BEFORE the barrier: vmcnt rides across it
#pragma unroll
        for (int r = 0; r < 4; ++r) {
            int t = base + 8 * (rq * 4 + r) + s + 1;
            t = t < 0 ? 0 : (t > T_LEN - 1 ? T_LEN - 1 : t);
            int o = obs[t];
#pragma unroll
            for (int nt = 0; nt < 2; ++nt)
                evn[nt][r] = E[(size_t)cols[nt] * NF + o] * SCALE;
        }

        sync_lds_only();
        const int rb = (s - 1) & 1, wb = s & 1;

        if (s == B_BN && tid < 256) {   // Q stitch: burned state at t=8c-1
            int g = tid >> 4, part = tid & 15;
            float ss = 0.f;
            const unsigned short* row = &xb[rb][g][part * 16];
#pragma unroll
            for (int i = 0; i < 16; ++i) ss += bs2f(row[i]);
#pragma unroll
            for (int m = 1; m < 16; m <<= 1) ss += __shfl_xor(ss, m, 16);
            if (part == 0) Qb[bid * G_CH + g] = log2f(ss);
        }

        // x A-frags (shared across both n-tiles): 8 x ds_read_b128
        short8 ax[8];
#pragma unroll
        for (int kk = 0; kk < 8; ++kk)
            ax[kk] = *(const short8*)&xb[rb][cj][kk * 32 + rq * 8];

        f32x4 acc[2];
#pragma unroll
        for (int nt = 0; nt < 2; ++nt) acc[nt] = (f32x4){0.f, 0.f, 0.f, 0.f};
#pragma unroll
        for (int kk = 0; kk < 8; ++kk) {
            acc[0] = __builtin_amdgcn_mfma_f32_16x16x32_bf16(ax[kk], bfr[0][kk], acc[0], 0, 0, 0);
            acc[1] = __builtin_amdgcn_mfma_f32_16x16x32_bf16(ax[kk], bfr[1][kk], acc[1], 0, 0, 0);
        }

        const bool body = (s >= B_BN);
#pragma unroll
        for (int nt = 0; nt < 2; ++nt) {
#pragma unroll
            for (int r = 0; r < 4; ++r) {
                int g = rq * 4 + r;
                float y = acc[nt][r] * evc[nt][r];
                bool skip = (bid == 0) && (s == B_BN) && (g == 0);
                if (!skip) {
                    unsigned short yb = (unsigned short)f2bs(y);
                    xb[wb][g][cols[nt]] = yb;
                    if (body) {
                        int tg = base + 8 * g + s;
                        zbuf[(size_t)tg * NS + cols[nt]] = yb;
                    }
                }
            }
        }

        // chain 0 exact re-init at s == B (t = 0)
        if (bid == 0 && s == B_BN && tid < 256) {
            float y0 = start[tid] * E[(size_t)tid * NF + obs0] * SCALE;
            unsigned short yb = (unsigned short)f2bs(y0);
            xb[wb][0][tid] = yb;
            zbuf[tid] = yb;
        }

#pragma unroll
        for (int nt = 0; nt < 2; ++nt)
#pragma unroll
            for (int r = 0; r < 4; ++r) evc[nt][r] = evn[nt][r];
    }

    // P stitch: chunk-end state at t = 8c+7, from xb[(S_TOT-1)&1] = xb[1]
    sync_lds_only();
    if (tid < 256) {
        int g = tid >> 4, part = tid & 15;
        float ss = 0.f;
        const unsigned short* row = &xb[1][g][part * 16];
#pragma unroll
        for (int i = 0; i < 16; ++i) ss += bs2f(row[i]);
#pragma unroll
        for (int m = 1; m < 16; m <<= 1) ss += __shfl_xor(ss, m, 16);
        if (part == 0) Pb[bid * G_CH + g] = log2f(ss);
    }
}

// ---- stitch: parallel f64 Kogge-Stone scan over 1024 chunk offsets --------
// P/Q are raw log2-sums; the -15(t+1) scaling telescopes exactly and is
// applied analytically here.
__global__ __launch_bounds__(1024)
void hmm_stitch(const float* __restrict__ Pb,
                const float* __restrict__ Qb,
                float* __restrict__ Dfull)
{
    __shared__ double x[C_CH];
    const int i = threadIdx.x;
    x[i] = (i == 0) ? 0.0 : ((double)Pb[i - 1] - (double)Qb[i]);
    __syncthreads();
    for (int ofs = 1; ofs < C_CH; ofs <<= 1) {
        double v = (i >= ofs) ? x[i - ofs] : 0.0;
        __syncthreads();
        x[i] += v;
        __syncthreads();
    }
    for (int t = i; t < T_LEN; t += 1024)
        Dfull[t] = (float)(x[t >> 3] - 15.0 * (double)(t + 1));
}

// ---- finalize: log2 + offset, 64x64 tiled transpose to [NS][T] ------------
__global__ __launch_bounds__(256)
void hmm_finalize(const unsigned short* __restrict__ zbuf,
                  const float* __restrict__ Dfull,
                  float* __restrict__ out)
{
    __shared__ float tile[64][65];
    const int t0   = blockIdx.x * 64;
    const int j0   = blockIdx.y * 64;
    const int lane = threadIdx.x & 63;
    const int row4 = threadIdx.x >> 6;
    const float LN2 = 0.69314718055994530942f;

#pragma unroll
    for (int r = 0; r < 16; ++r) {
        int trow = r * 4 + row4;
        int t = t0 + trow;
        float z = bs2f((short)zbuf[(size_t)t * NS + j0 + lane]);
        tile[trow][lane] = __log2f(z) + Dfull[t];
    }
    __syncthreads();
#pragma unroll
    for (int r = 0; r < 16; ++r) {
        int jrow = r * 4 + row4;
        out[(size_t)(j0 + jrow) * T_LEN + t0 + lane] = LN2 * tile[lane][jrow];
    }
}

// ---- fallback: single-workgroup sequential --------------------------------
__global__ __launch_bounds__(NS, 1)
void hmm_forward_seq(const float* __restrict__ start,
                     const float* __restrict__ A,
                     const float* __restrict__ E,
                     const int* __restrict__ obs,
                     float* __restrict__ out)
{
    __shared__ float xbuf[2][NS];
    __shared__ float red[4];
    const int j = threadIdx.x;
    float a[NS];
#pragma unroll
    for (int i = 0; i < NS; ++i) a[i] = A[i * NS + j];
    const float LN2 = 0.69314718055994530942f;
    float Eacc = 0.0f;
    float z = start[j] * E[(size_t)j * NF + obs[0]] * SCALE;
    out[(size_t)j * T_LEN + 0] = LN2 * (__log2f(z) - 15.0f);
    xbuf[0][j] = z;
    __syncthreads();
    float se_cur = E[(size_t)j * NF + obs[1]] * SCALE;
    for (int t = 1; t < T_LEN; ++t) {
        float se_nxt = 0.0f;
        if (t + 1 < T_LEN) se_nxt = E[(size_t)j * NF + obs[t + 1]] * SCALE;
        const float4* x4 = (const float4*)xbuf[(t - 1) & 1];
        float y0 = 0.f, y1 = 0.f, y2 = 0.f, y3 = 0.f;
#pragma unroll
        for (int i = 0; i < NS / 4; ++i) {
            float4 xv = x4[i];
            y0 = fmaf(xv.x, a[4 * i + 0], y0);
            y1 = fmaf(xv.y, a[4 * i + 1], y1);
            y2 = fmaf(xv.z, a[4 * i + 2], y2);
            y3 = fmaf(xv.w, a[4 * i + 3], y3);
        }
        float y = ((y0 + y1) + (y2 + y3)) * se_cur;
        se_cur = se_nxt;
        out[(size_t)j * T_LEN + t] =
            LN2 * (__log2f(y) + Eacc - 15.0f * (float)(t + 1));
        float* wr = xbuf[t & 1];
        wr[j] = y;
        __syncthreads();
        if ((t & 1023) == 1023) {
            float v = wr[j];
#pragma unroll
            for (int d = 1; d < 64; d <<= 1) v = fmaxf(v, __shfl_xor(v, d, 64));
            if ((j & 63) == 0) red[j >> 6] = v;
            __syncthreads();
            float m = fmaxf(fmaxf(red[0], red[1]), fmaxf(red[2], red[3]));
            int k = ilogbf(m);
            wr[j] = ldexpf(wr[j], -k);
            Eacc += (float)k;
            __syncthreads();
        }
    }
}

extern "C" void kernel_launch(void* const* d_in, const int* in_sizes, int n_in,
                              void* d_out, int out_size, void* d_ws, size_t ws_size,
                              hipStream_t stream) {
    const float* start = (const float*)d_in[0];
    const float* A     = (const float*)d_in[1];
    const float* E     = (const float*)d_in[2];
    const int*   obs   = (const int*)d_in[3];
    float* out = (float*)d_out;

    char* ws = (char*)d_ws;
    const size_t zb_bytes = (size_t)T_LEN * NS * sizeof(unsigned short);  // 4 MB

    unsigned short* z = (unsigned short*)ws;
    float* Pb    = (float*)(ws + zb_bytes);
    float* Qb    = Pb + C_CH;
    float* Dfull = Qb + C_CH;

    const size_t need = zb_bytes + (2 * C_CH + T_LEN) * sizeof(float);

    if (ws_size >= need) {
        hmm_chains<<<NBLK, 512, 0, stream>>>(start, A, E, obs, z, Pb, Qb);
        hmm_stitch<<<1, 1024, 0, stream>>>(Pb, Qb, Dfull);
        hmm_finalize<<<dim3(T_LEN / 64, NS / 64), 256, 0, stream>>>(z, Dfull, out);
    } else {
        hmm_forward_seq<<<1, NS, 0, stream>>>(start, A, E, obs, out);
    }
}

// Round 10
// 42.578 us; speedup vs baseline: 2.7784x; 2.7784x over previous
//
#include <hip/hip_runtime.h>
#include <hip/hip_bf16.h>
#include <math.h>

#define NS 256
#define T_LEN 8192
#define NF 32000
#define L_CH 8
#define B_BN 8
#define S_TOT 16          // B_BN + L_CH
#define C_CH 1024         // T_LEN / L_CH
#define G_CH 16           // chains per block
#define NBLK 64           // C_CH / G_CH
#define SCALE 32768.0f
#define XPAD 264          // shorts per x-row (528 B)
#define TCHUNK 512

typedef short short8 __attribute__((ext_vector_type(8)));
typedef float f32x4 __attribute__((ext_vector_type(4)));

__device__ __forceinline__ short f2bs(float f) {
    union { __bf16 b; short s; } u; u.b = (__bf16)f; return u.s;
}
__device__ __forceinline__ float bs2f(short s) {
    union { short s; __bf16 b; } u; u.s = s; return (float)u.b;
}

// LDS-only barrier: drain own LDS ops, sync; global loads/stores ride across.
__device__ __forceinline__ void sync_lds_only() {
    __builtin_amdgcn_sched_barrier(0);
    asm volatile("s_waitcnt lgkmcnt(0)" ::: "memory");
    __builtin_amdgcn_s_barrier();
    __builtin_amdgcn_sched_barrier(0);
}

// ---- prep: L2-local SE gather (blocks 0..255) + A swizzle (blocks 256..287)
// Gather block (jg, tc): jg = bid & 15 so all t-chunks of a j-group land on
// the same XCD (bid mod 8 = jg mod 8) -> the group's 2 MB of E rows stays L2.
__global__ __launch_bounds__(256)
void prep(const float* __restrict__ E, const int* __restrict__ obs,
          const float* __restrict__ A,
          float* __restrict__ SE, short* __restrict__ Aswz) {
    const int bid = blockIdx.x;
    if (bid < 256) {
        const int jg = bid & 15, tc = bid >> 4;
        const int t0 = tc * TCHUNK;
        __shared__ int olds[TCHUNK];
        for (int i = threadIdx.x; i < TCHUNK; i += 256)
            olds[i] = obs[t0 + i];
        __syncthreads();
        const int jl = threadIdx.x & 15;   // j within group
        const int tl = threadIdx.x >> 4;   // 0..15
        const int j  = jg * 16 + jl;
        const float* Erow = E + (size_t)j * NF;
#pragma unroll 4
        for (int p = 0; p < TCHUNK / 16; ++p) {
            int t_loc = p * 16 + tl;
            int o = olds[t_loc];
            SE[(size_t)(t0 + t_loc) * NS + j] = Erow[o] * SCALE;
        }
    } else if (bid < 288) {
        // A swizzle: pb = frag-group 0..127, one per wave
        const int pb   = (bid - 256) * 4 + (threadIdx.x >> 6);
        const int lane = threadIdx.x & 63;
        const int ntg  = pb >> 3;          // 0..15
        const int kk   = pb & 7;           // 0..7
        const int col  = ntg * 16 + (lane & 15);
        const int krow = kk * 32 + (lane >> 4) * 8;
        short8 v;
#pragma unroll
        for (int e = 0; e < 8; ++e)
            v[e] = f2bs(A[(size_t)(krow + e) * NS + col]);
        *(short8*)&Aswz[((size_t)pb * 64 + lane) * 8] = v;
    }
}

// ---- chained MFMA steps: 64 blocks x 1024 threads (16 waves), 16 chains ---
// Wave wv owns n-tile wv (cols 16wv..16wv+15): bfr = 8 x short8 = 32 VGPRs.
__global__ __launch_bounds__(1024, 4)
void hmm_chains(const float* __restrict__ start,
                const float* __restrict__ SE,
                const short* __restrict__ Aswz,
                unsigned short* __restrict__ zbuf,   // [T][NS] bf16
                float* __restrict__ Pb, float* __restrict__ Qb)
{
    const int bid  = blockIdx.x;
    const int tid  = threadIdx.x;
    const int wv   = tid >> 6;          // wave 0..15 = n-tile
    const int lane = tid & 63;
    const int cj   = lane & 15;
    const int rq   = lane >> 4;
    const int col  = wv * 16 + cj;
    const int base = 128 * bid - B_BN;  // t = base + 8*g + s

    __shared__ unsigned short xb[2][G_CH][XPAD];

    // this wave's B-fragments of A: 8 x short8 = 32 VGPRs
    short8 bfr[8];
    const short8* Av = (const short8*)Aswz;
#pragma unroll
    for (int kk = 0; kk < 8; ++kk)
        bfr[kk] = Av[((size_t)(wv * 8 + kk)) * 64 + lane];
#pragma unroll
    for (int kk = 0; kk < 8; ++kk)
        asm volatile("" : "+v"(bfr[kk]));

    // burn-in start: x = 1 (bf16 0x3F80)
    for (int idx = tid; idx < G_CH * XPAD; idx += 1024)
        ((unsigned short*)xb[0])[idx] = 0x3F80;

    // prologue: emissions for s = 1 (4 per lane: rows g = rq*4+r)
    float evc[4], evn[4];
#pragma unroll
    for (int r = 0; r < 4; ++r) {
        int t = base + 8 * (rq * 4 + r) + 1;
        t = t < 0 ? 0 : t;
        evc[r] = SE[(size_t)t * NS + col];
    }

    for (int s = 1; s < S_TOT; ++s) {
        sync_lds_only();
        const int rb = (s - 1) & 1, wb = s & 1;

        if (s == B_BN && tid < 256) {   // Q stitch: burned state at t = 8c-1
            int g = tid >> 4, part = tid & 15;
            float ss = 0.f;
            const unsigned short* row = &xb[rb][g][part * 16];
#pragma unroll
            for (int i = 0; i < 16; ++i) ss += bs2f(row[i]);
#pragma unroll
            for (int m = 1; m < 16; m <<= 1) ss += __shfl_xor(ss, m, 16);
            if (part == 0) Qb[bid * G_CH + g] = log2f(ss);
        }

        // prefetch emissions for s+1 (dense SE rows)
#pragma unroll
        for (int r = 0; r < 4; ++r) {
            int t = base + 8 * (rq * 4 + r) + s + 1;
            t = t < 0 ? 0 : (t > T_LEN - 1 ? T_LEN - 1 : t);
            evn[r] = SE[(size_t)t * NS + col];
        }

        // x A-frags: lane holds x[m=cj][k = kk*32 + rq*8 + 0..7]
        short8 ax[8];
#pragma unroll
        for (int kk = 0; kk < 8; ++kk)
            ax[kk] = *(const short8*)&xb[rb][cj][kk * 32 + rq * 8];

        f32x4 acc = (f32x4){0.f, 0.f, 0.f, 0.f};
#pragma unroll
        for (int kk = 0; kk < 8; ++kk)
            acc = __builtin_amdgcn_mfma_f32_16x16x32_bf16(ax[kk], bfr[kk], acc, 0, 0, 0);

        const bool body = (s >= B_BN);
#pragma unroll
        for (int r = 0; r < 4; ++r) {
            int g = rq * 4 + r;
            float y = acc[r] * evc[r];
            bool skip = (bid == 0) && (s == B_BN) && (g == 0);
            if (!skip) {
                unsigned short yb = (unsigned short)f2bs(y);
                xb[wb][g][col] = yb;
                if (body) {
                    int tg = base + 8 * g + s;
                    zbuf[(size_t)tg * NS + col] = yb;
                }
            }
        }

        // chain 0 exact re-init at s == B (t = 0)
        if (bid == 0 && s == B_BN && tid < 256) {
            float y0 = start[tid] * SE[tid];
            unsigned short yb = (unsigned short)f2bs(y0);
            xb[wb][0][tid] = yb;
            zbuf[tid] = yb;
        }

#pragma unroll
        for (int r = 0; r < 4; ++r) evc[r] = evn[r];
    }

    // P stitch: chunk-end state at t = 8c+7, from xb[(S_TOT-1)&1] = xb[1]
    sync_lds_only();
    if (tid < 256) {
        int g = tid >> 4, part = tid & 15;
        float ss = 0.f;
        const unsigned short* row = &xb[1][g][part * 16];
#pragma unroll
        for (int i = 0; i < 16; ++i) ss += bs2f(row[i]);
#pragma unroll
        for (int m = 1; m < 16; m <<= 1) ss += __shfl_xor(ss, m, 16);
        if (part == 0) Pb[bid * G_CH + g] = log2f(ss);
    }
}

// ---- stitch: parallel f64 Kogge-Stone scan over 1024 chunk offsets --------
__global__ __launch_bounds__(1024)
void hmm_stitch(const float* __restrict__ Pb,
                const float* __restrict__ Qb,
                float* __restrict__ Dfull)
{
    __shared__ double x[C_CH];
    const int i = threadIdx.x;
    x[i] = (i == 0) ? 0.0 : ((double)Pb[i - 1] - (double)Qb[i]);
    __syncthreads();
    for (int ofs = 1; ofs < C_CH; ofs <<= 1) {
        double v = (i >= ofs) ? x[i - ofs] : 0.0;
        __syncthreads();
        x[i] += v;
        __syncthreads();
    }
    for (int t = i; t < T_LEN; t += 1024)
        Dfull[t] = (float)(x[t >> 3] - 15.0 * (double)(t + 1));
}

// ---- finalize: log2 + offset, 64x64 tiled transpose to [NS][T] ------------
__global__ __launch_bounds__(256)
void hmm_finalize(const unsigned short* __restrict__ zbuf,
                  const float* __restrict__ Dfull,
                  float* __restrict__ out)
{
    __shared__ float tile[64][65];
    const int t0   = blockIdx.x * 64;
    const int j0   = blockIdx.y * 64;
    const int lane = threadIdx.x & 63;
    const int row4 = threadIdx.x >> 6;
    const float LN2 = 0.69314718055994530942f;

#pragma unroll
    for (int r = 0; r < 16; ++r) {
        int trow = r * 4 + row4;
        int t = t0 + trow;
        float z = bs2f((short)zbuf[(size_t)t * NS + j0 + lane]);
        tile[trow][lane] = __log2f(z) + Dfull[t];
    }
    __syncthreads();
#pragma unroll
    for (int r = 0; r < 16; ++r) {
        int jrow = r * 4 + row4;
        out[(size_t)(j0 + jrow) * T_LEN + t0 + lane] = LN2 * tile[lane][jrow];
    }
}

// ---- fallback: single-workgroup sequential --------------------------------
__global__ __launch_bounds__(NS, 1)
void hmm_forward_seq(const float* __restrict__ start,
                     const float* __restrict__ A,
                     const float* __restrict__ E,
                     const int* __restrict__ obs,
                     float* __restrict__ out)
{
    __shared__ float xbuf[2][NS];
    __shared__ float red[4];
    const int j = threadIdx.x;
    float a[NS];
#pragma unroll
    for (int i = 0; i < NS; ++i) a[i] = A[i * NS + j];
    const float LN2 = 0.69314718055994530942f;
    float Eacc = 0.0f;
    float z = start[j] * E[(size_t)j * NF + obs[0]] * SCALE;
    out[(size_t)j * T_LEN + 0] = LN2 * (__log2f(z) - 15.0f);
    xbuf[0][j] = z;
    __syncthreads();
    float se_cur = E[(size_t)j * NF + obs[1]] * SCALE;
    for (int t = 1; t < T_LEN; ++t) {
        float se_nxt = 0.0f;
        if (t + 1 < T_LEN) se_nxt = E[(size_t)j * NF + obs[t + 1]] * SCALE;
        const float4* x4 = (const float4*)xbuf[(t - 1) & 1];
        float y0 = 0.f, y1 = 0.f, y2 = 0.f, y3 = 0.f;
#pragma unroll
        for (int i = 0; i < NS / 4; ++i) {
            float4 xv = x4[i];
            y0 = fmaf(xv.x, a[4 * i + 0], y0);
            y1 = fmaf(xv.y, a[4 * i + 1], y1);
            y2 = fmaf(xv.z, a[4 * i + 2], y2);
            y3 = fmaf(xv.w, a[4 * i + 3], y3);
        }
        float y = ((y0 + y1) + (y2 + y3)) * se_cur;
        se_cur = se_nxt;
        out[(size_t)j * T_LEN + t] =
            LN2 * (__log2f(y) + Eacc - 15.0f * (float)(t + 1));
        float* wr = xbuf[t & 1];
        wr[j] = y;
        __syncthreads();
        if ((t & 1023) == 1023) {
            float v = wr[j];
#pragma unroll
            for (int d = 1; d < 64; d <<= 1) v = fmaxf(v, __shfl_xor(v, d, 64));
            if ((j & 63) == 0) red[j >> 6] = v;
            __syncthreads();
            float m = fmaxf(fmaxf(red[0], red[1]), fmaxf(red[2], red[3]));
            int k = ilogbf(m);
            wr[j] = ldexpf(wr[j], -k);
            Eacc += (float)k;
            __syncthreads();
        }
    }
}

extern "C" void kernel_launch(void* const* d_in, const int* in_sizes, int n_in,
                              void* d_out, int out_size, void* d_ws, size_t ws_size,
                              hipStream_t stream) {
    const float* start = (const float*)d_in[0];
    const float* A     = (const float*)d_in[1];
    const float* E     = (const float*)d_in[2];
    const int*   obs   = (const int*)d_in[3];
    float* out = (float*)d_out;

    char* ws = (char*)d_ws;
    const size_t zb_bytes  = (size_t)T_LEN * NS * sizeof(unsigned short);  // 4 MB
    const size_t se_bytes  = (size_t)T_LEN * NS * sizeof(float);           // 8 MB
    const size_t asw_bytes = (size_t)128 * 64 * 8 * sizeof(short);         // 128 KB

    unsigned short* z = (unsigned short*)ws;
    float* SE    = (float*)(ws + zb_bytes);
    short* Aswz  = (short*)(ws + zb_bytes + se_bytes);
    float* Pb    = (float*)(ws + zb_bytes + se_bytes + asw_bytes);
    float* Qb    = Pb + C_CH;
    float* Dfull = Qb + C_CH;

    const size_t need = zb_bytes + se_bytes + asw_bytes +
                        (2 * C_CH + T_LEN) * sizeof(float);

    if (ws_size >= need) {
        prep<<<288, 256, 0, stream>>>(E, obs, A, SE, Aswz);
        hmm_chains<<<NBLK, 1024, 0, stream>>>(start, SE, Aswz, z, Pb, Qb);
        hmm_stitch<<<1, 1024, 0, stream>>>(Pb, Qb, Dfull);
        hmm_finalize<<<dim3(T_LEN / 64, NS / 64), 256, 0, stream>>>(z, Dfull, out);
    } else {
        hmm_forward_seq<<<1, NS, 0, stream>>>(start, A, E, obs, out);
    }
}

// Round 11
// 37.948 us; speedup vs baseline: 3.1174x; 1.1220x over previous
//
#include <hip/hip_runtime.h>
#include <hip/hip_bf16.h>
#include <math.h>

#define NS 256
#define T_LEN 8192
#define NF 32000
#define L_CH 2
#define B_BN 8
#define S_TOT 10          // B_BN + L_CH
#define C_CH 4096         // T_LEN / L_CH
#define G_CH 16           // chains per block
#define NBLK 256          // C_CH / G_CH
#define SCALE 32768.0f
#define XPAD 264          // shorts per x-row (528 B)
#define TCHUNK 512

typedef short short8 __attribute__((ext_vector_type(8)));
typedef float f32x4 __attribute__((ext_vector_type(4)));

__device__ __forceinline__ short f2bs(float f) {
    union { __bf16 b; short s; } u; u.b = (__bf16)f; return u.s;
}
__device__ __forceinline__ float bs2f(short s) {
    union { short s; __bf16 b; } u; u.s = s; return (float)u.b;
}

// LDS-only barrier: drain own LDS ops, sync; global loads/stores ride across.
__device__ __forceinline__ void sync_lds_only() {
    __builtin_amdgcn_sched_barrier(0);
    asm volatile("s_waitcnt lgkmcnt(0)" ::: "memory");
    __builtin_amdgcn_s_barrier();
    __builtin_amdgcn_sched_barrier(0);
}

// ---- prep: L2-local SE gather (blocks 0..255, bf16) + A swizzle (256..287)
__global__ __launch_bounds__(256)
void prep(const float* __restrict__ E, const int* __restrict__ obs,
          const float* __restrict__ A,
          unsigned short* __restrict__ SEb, short* __restrict__ Aswz) {
    const int bid = blockIdx.x;
    if (bid < 256) {
        const int jg = bid & 15, tc = bid >> 4;
        const int t0 = tc * TCHUNK;
        __shared__ int olds[TCHUNK];
        for (int i = threadIdx.x; i < TCHUNK; i += 256)
            olds[i] = obs[t0 + i];
        __syncthreads();
        const int jl = threadIdx.x & 15;   // j within group
        const int tl = threadIdx.x >> 4;   // 0..15
        const int j  = jg * 16 + jl;
        const float* Erow = E + (size_t)j * NF;
#pragma unroll 4
        for (int p = 0; p < TCHUNK / 16; ++p) {
            int t_loc = p * 16 + tl;
            int o = olds[t_loc];
            SEb[(size_t)(t0 + t_loc) * NS + j] =
                (unsigned short)f2bs(Erow[o] * SCALE);
        }
    } else if (bid < 288) {
        const int pb   = (bid - 256) * 4 + (threadIdx.x >> 6);  // 0..127
        const int lane = threadIdx.x & 63;
        const int ntg  = pb >> 3;
        const int kk   = pb & 7;
        const int col  = ntg * 16 + (lane & 15);
        const int krow = kk * 32 + (lane >> 4) * 8;
        short8 v;
#pragma unroll
        for (int e = 0; e < 8; ++e)
            v[e] = f2bs(A[(size_t)(krow + e) * NS + col]);
        *(short8*)&Aswz[((size_t)pb * 64 + lane) * 8] = v;
    }
}

// ---- chained MFMA steps: 256 blocks x 1024 threads (16 waves), 16 chains --
__global__ __launch_bounds__(1024, 4)
void hmm_chains(const float* __restrict__ start,
                const unsigned short* __restrict__ SEb,
                const short* __restrict__ Aswz,
                unsigned short* __restrict__ zbuf,   // [T][NS] bf16
                float* __restrict__ Pb, float* __restrict__ Qb)
{
    const int bid  = blockIdx.x;
    const int tid  = threadIdx.x;
    const int wv   = tid >> 6;          // wave 0..15 = n-tile
    const int lane = tid & 63;
    const int cj   = lane & 15;
    const int rq   = lane >> 4;
    const int col  = wv * 16 + cj;
    const int base = 32 * bid - B_BN;   // t = base + 2*g + s

    __shared__ unsigned short xb[2][G_CH][XPAD];

    // this wave's B-fragments of A: 8 x short8 = 32 VGPRs
    short8 bfr[8];
    const short8* Av = (const short8*)Aswz;
#pragma unroll
    for (int kk = 0; kk < 8; ++kk)
        bfr[kk] = Av[((size_t)(wv * 8 + kk)) * 64 + lane];
#pragma unroll
    for (int kk = 0; kk < 8; ++kk)
        asm volatile("" : "+v"(bfr[kk]));

    // burn-in start: x = 1 (bf16 0x3F80)
    for (int idx = tid; idx < G_CH * XPAD; idx += 1024)
        ((unsigned short*)xb[0])[idx] = 0x3F80;

    // prologue: emissions for s = 1
    float evc[4], evn[4];
#pragma unroll
    for (int r = 0; r < 4; ++r) {
        int t = base + 2 * (rq * 4 + r) + 1;
        t = t < 0 ? 0 : t;
        evc[r] = bs2f((short)SEb[(size_t)t * NS + col]);
    }

    for (int s = 1; s < S_TOT; ++s) {
        sync_lds_only();
        const int rb = (s - 1) & 1, wb = s & 1;

        if (s == B_BN && tid < 256) {   // Q stitch: burned state at t = t0-1
            int g = tid >> 4, part = tid & 15;
            float ss = 0.f;
            const unsigned short* row = &xb[rb][g][part * 16];
#pragma unroll
            for (int i = 0; i < 16; ++i) ss += bs2f(row[i]);
#pragma unroll
            for (int m = 1; m < 16; m <<= 1) ss += __shfl_xor(ss, m, 16);
            if (part == 0) Qb[bid * G_CH + g] = log2f(ss);
        }

        // prefetch emissions for s+1 (dense bf16 SE rows)
#pragma unroll
        for (int r = 0; r < 4; ++r) {
            int t = base + 2 * (rq * 4 + r) + s + 1;
            t = t < 0 ? 0 : (t > T_LEN - 1 ? T_LEN - 1 : t);
            evn[r] = bs2f((short)SEb[(size_t)t * NS + col]);
        }

        // x A-frags: lane holds x[m=cj][k = kk*32 + rq*8 + 0..7]
        short8 ax[8];
#pragma unroll
        for (int kk = 0; kk < 8; ++kk)
            ax[kk] = *(const short8*)&xb[rb][cj][kk * 32 + rq * 8];

        f32x4 acc = (f32x4){0.f, 0.f, 0.f, 0.f};
#pragma unroll
        for (int kk = 0; kk < 8; ++kk)
            acc = __builtin_amdgcn_mfma_f32_16x16x32_bf16(ax[kk], bfr[kk], acc, 0, 0, 0);

        const bool body = (s >= B_BN);
#pragma unroll
        for (int r = 0; r < 4; ++r) {
            int g = rq * 4 + r;
            float y = acc[r] * evc[r];
            bool skip = (bid == 0) && (s == B_BN) && (g == 0);
            if (!skip) {
                unsigned short yb = (unsigned short)f2bs(y);
                xb[wb][g][col] = yb;
                if (body) {
                    int tg = base + 2 * g + s;
                    zbuf[(size_t)tg * NS + col] = yb;
                }
            }
        }

        // chain (0,0) exact re-init at s == B (t = 0)
        if (bid == 0 && s == B_BN && tid < 256) {
            float y0 = start[tid] * bs2f((short)SEb[tid]);
            unsigned short yb = (unsigned short)f2bs(y0);
            xb[wb][0][tid] = yb;
            zbuf[tid] = yb;
        }

#pragma unroll
        for (int r = 0; r < 4; ++r) evc[r] = evn[r];
    }

    // P stitch: chunk-end state at t = t0+1, from xb[(S_TOT-1)&1] = xb[1]
    sync_lds_only();
    if (tid < 256) {
        int g = tid >> 4, part = tid & 15;
        float ss = 0.f;
        const unsigned short* row = &xb[1][g][part * 16];
#pragma unroll
        for (int i = 0; i < 16; ++i) ss += bs2f(row[i]);
#pragma unroll
        for (int m = 1; m < 16; m <<= 1) ss += __shfl_xor(ss, m, 16);
        if (part == 0) Pb[bid * G_CH + g] = log2f(ss);
    }
}

// ---- stitch: 4096-chunk f64 scan (4/thread serial + 1024-wide KS) ---------
__global__ __launch_bounds__(1024)
void hmm_stitch(const float* __restrict__ Pb,
                const float* __restrict__ Qb,
                float* __restrict__ Dfull)
{
    __shared__ double xs[1024];
    const int tid = threadIdx.x;
    double loc[4];
    double s = 0.0;
#pragma unroll
    for (int i = 0; i < 4; ++i) {
        int cc = tid * 4 + i;
        double d = (cc == 0) ? 0.0 : ((double)Pb[cc - 1] - (double)Qb[cc]);
        s += d;
        loc[i] = s;
    }
    xs[tid] = s;
    __syncthreads();
    for (int ofs = 1; ofs < 1024; ofs <<= 1) {
        double v = (tid >= ofs) ? xs[tid - ofs] : 0.0;
        __syncthreads();
        xs[tid] += v;
        __syncthreads();
    }
    const double off = xs[tid] - s;   // exclusive prefix of thread sums
#pragma unroll
    for (int i = 0; i < 4; ++i) {
        double D = off + loc[i];
        int t0 = (tid * 4 + i) * 2;
        Dfull[t0]     = (float)(D - 15.0 * (double)(t0 + 1));
        Dfull[t0 + 1] = (float)(D - 15.0 * (double)(t0 + 2));
    }
}

// ---- finalize: log2 + offset, 64x64 tiled transpose to [NS][T] ------------
__global__ __launch_bounds__(256)
void hmm_finalize(const unsigned short* __restrict__ zbuf,
                  const float* __restrict__ Dfull,
                  float* __restrict__ out)
{
    __shared__ float tile[64][65];
    const int t0   = blockIdx.x * 64;
    const int j0   = blockIdx.y * 64;
    const int lane = threadIdx.x & 63;
    const int row4 = threadIdx.x >> 6;
    const float LN2 = 0.69314718055994530942f;

#pragma unroll
    for (int r = 0; r < 16; ++r) {
        int trow = r * 4 + row4;
        int t = t0 + trow;
        float z = bs2f((short)zbuf[(size_t)t * NS + j0 + lane]);
        tile[trow][lane] = __log2f(z) + Dfull[t];
    }
    __syncthreads();
#pragma unroll
    for (int r = 0; r < 16; ++r) {
        int jrow = r * 4 + row4;
        out[(size_t)(j0 + jrow) * T_LEN + t0 + lane] = LN2 * tile[lane][jrow];
    }
}

// ---- fallback: single-workgroup sequential --------------------------------
__global__ __launch_bounds__(NS, 1)
void hmm_forward_seq(const float* __restrict__ start,
                     const float* __restrict__ A,
                     const float* __restrict__ E,
                     const int* __restrict__ obs,
                     float* __restrict__ out)
{
    __shared__ float xbuf[2][NS];
    __shared__ float red[4];
    const int j = threadIdx.x;
    float a[NS];
#pragma unroll
    for (int i = 0; i < NS; ++i) a[i] = A[i * NS + j];
    const float LN2 = 0.69314718055994530942f;
    float Eacc = 0.0f;
    float z = start[j] * E[(size_t)j * NF + obs[0]] * SCALE;
    out[(size_t)j * T_LEN + 0] = LN2 * (__log2f(z) - 15.0f);
    xbuf[0][j] = z;
    __syncthreads();
    float se_cur = E[(size_t)j * NF + obs[1]] * SCALE;
    for (int t = 1; t < T_LEN; ++t) {
        float se_nxt = 0.0f;
        if (t + 1 < T_LEN) se_nxt = E[(size_t)j * NF + obs[t + 1]] * SCALE;
        const float4* x4 = (const float4*)xbuf[(t - 1) & 1];
        float y0 = 0.f, y1 = 0.f, y2 = 0.f, y3 = 0.f;
#pragma unroll
        for (int i = 0; i < NS / 4; ++i) {
            float4 xv = x4[i];
            y0 = fmaf(xv.x, a[4 * i + 0], y0);
            y1 = fmaf(xv.y, a[4 * i + 1], y1);
            y2 = fmaf(xv.z, a[4 * i + 2], y2);
            y3 = fmaf(xv.w, a[4 * i + 3], y3);
        }
        float y = ((y0 + y1) + (y2 + y3)) * se_cur;
        se_cur = se_nxt;
        out[(size_t)j * T_LEN + t] =
            LN2 * (__log2f(y) + Eacc - 15.0f * (float)(t + 1));
        float* wr = xbuf[t & 1];
        wr[j] = y;
        __syncthreads();
        if ((t & 1023) == 1023) {
            float v = wr[j];
#pragma unroll
            for (int d = 1; d < 64; d <<= 1) v = fmaxf(v, __shfl_xor(v, d, 64));
            if ((j & 63) == 0) red[j >> 6] = v;
            __syncthreads();
            float m = fmaxf(fmaxf(red[0], red[1]), fmaxf(red[2], red[3]));
            int k = ilogbf(m);
            wr[j] = ldexpf(wr[j], -k);
            Eacc += (float)k;
            __syncthreads();
        }
    }
}

extern "C" void kernel_launch(void* const* d_in, const int* in_sizes, int n_in,
                              void* d_out, int out_size, void* d_ws, size_t ws_size,
                              hipStream_t stream) {
    const float* start = (const float*)d_in[0];
    const float* A     = (const float*)d_in[1];
    const float* E     = (const float*)d_in[2];
    const int*   obs   = (const int*)d_in[3];
    float* out = (float*)d_out;

    char* ws = (char*)d_ws;
    const size_t zb_bytes  = (size_t)T_LEN * NS * sizeof(unsigned short);  // 4 MB
    const size_t se_bytes  = (size_t)T_LEN * NS * sizeof(unsigned short);  // 4 MB
    const size_t asw_bytes = (size_t)128 * 64 * 8 * sizeof(short);         // 128 KB

    unsigned short* z   = (unsigned short*)ws;
    unsigned short* SEb = (unsigned short*)(ws + zb_bytes);
    short* Aswz  = (short*)(ws + zb_bytes + se_bytes);
    float* Pb    = (float*)(ws + zb_bytes + se_bytes + asw_bytes);
    float* Qb    = Pb + C_CH;
    float* Dfull = Qb + C_CH;

    const size_t need = zb_bytes + se_bytes + asw_bytes +
                        (2 * C_CH + T_LEN) * sizeof(float);

    if (ws_size >= need) {
        prep<<<288, 256, 0, stream>>>(E, obs, A, SEb, Aswz);
        hmm_chains<<<NBLK, 1024, 0, stream>>>(start, SEb, Aswz, z, Pb, Qb);
        hmm_stitch<<<1, 1024, 0, stream>>>(Pb, Qb, Dfull);
        hmm_finalize<<<dim3(T_LEN / 64, NS / 64), 256, 0, stream>>>(z, Dfull, out);
    } else {
        hmm_forward_seq<<<1, NS, 0, stream>>>(start, A, E, obs, out);
    }
}